// Round 6
// baseline (281.379 us; speedup 1.0000x reference)
//
#include <hip/hip_runtime.h>

typedef unsigned int u32;
typedef unsigned char u8;
typedef unsigned long long u64;
typedef int i32x4 __attribute__((ext_vector_type(4)));
typedef int i32x16 __attribute__((ext_vector_type(16)));

// Workspace layout (3.8 MB used):
//   [0, 589824)          Wm[step=tap*8+kc][oc][ic32] i8 (+/-1), 8KB per step
//   [589824, +3211264)   bp bitplanes: bp[(n*256+ch)*49 + (px>>6)], bit px&63
#define WM_OFF 0
#define BP_OFF 589824

// ---------------------------------------------------------------------------
// Kernel 1: prep = pack_w (blocks 0..2303) + bin_bits (blocks 2304..3871).
// ---------------------------------------------------------------------------
__global__ __launch_bounds__(256) void prep(const int* __restrict__ enc,
                                            const float* __restrict__ cb,
                                            char* __restrict__ wm,
                                            const float* __restrict__ x,
                                            u64* __restrict__ bp) {
    int bid = blockIdx.x;
    if (bid < 2304) {
        int idx  = bid * 256 + threadIdx.x;          // 0..589823
        int icin = idx & 31;
        int oc   = (idx >> 5) & 255;
        int step = idx >> 13;                        // 0..71 = tap*8+kc
        int tap  = step >> 3;
        int kc   = step & 7;
        int i = kc * 32 + icin;
        int f = oc * 2304 + i * 9 + tap;             // OIHW flat index
        int j = f / 12;
        int t = f - j * 12;
        float v = cb[enc[j] * 12 + t];
        wm[idx] = v < 0.f ? (char)-1 : (char)1;
    } else {
        int gw   = (bid - 2304) * 4 + (threadIdx.x >> 6);  // 0..6271
        int lane = threadIdx.x & 63;
        const float* xb = x + (size_t)gw * 4096 + lane;
#pragma unroll 1
        for (int k = 0; k < 8; ++k) {
            float v[8];
#pragma unroll
            for (int j = 0; j < 8; ++j) v[j] = xb[k * 512 + j * 64];
            u64 mine = 0;
#pragma unroll
            for (int j = 0; j < 8; ++j) {
                u64 m = __ballot(v[j] < 0.f);
                if (lane == j) mine = m;
            }
            if (lane < 8) bp[(size_t)gw * 64 + k * 8 + lane] = mine;
        }
    }
}

// ---------------------------------------------------------------------------
// Expand one padded row of bitplanes into the swizzled LDS X-tile.
// thread (oct, wseg): channels oct*8..+8, w' = wseg+4k. 16 bp loads (L2-hot),
// 15 u64 LDS writes at [wq*256 + (oct*8 ^ ((wq&15)<<4))].
// ---------------------------------------------------------------------------
__device__ __forceinline__ void expand_row(const u64* __restrict__ bp, u8* xr,
                                           int n, int h, int oct, int wseg) {
    bool rowv = (h >= 0) && (h <= 55);
    int w0c = rowv ? ((h * 56) >> 6) : 0;
    int w1c = w0c + 1; if (w1c > 48) w1c = 48;
    const u64* bq = bp + ((size_t)n * 256 + oct * 8) * 49;
    u64 A[8], B[8];
#pragma unroll
    for (int j = 0; j < 8; ++j) A[j] = bq[j * 49 + w0c];
#pragma unroll
    for (int j = 0; j < 8; ++j) B[j] = bq[j * 49 + w1c];
#pragma unroll 1
    for (int k = 0; k < 15; ++k) {
        int wq = wseg + k * 4;
        if (wq >= 58) break;
        u64 out = 0;
        if (rowv && wq >= 1 && wq <= 56) {
            int px  = h * 56 + wq - 1;
            int bit = px & 63;
            bool s2 = (px >> 6) != w0c;
#pragma unroll
            for (int j = 0; j < 8; ++j) {
                u64 wv = s2 ? B[j] : A[j];
                out |= (((wv >> bit) & 1ull) ? 0xFFull : 0x01ull) << (8 * j);
            }
        }
        *(u64*)(xr + wq * 256 + ((oct * 8) ^ ((wq & 15) << 4))) = out;
    }
}

// ---------------------------------------------------------------------------
// Kernel 2: i8 MFMA conv. 512 thr, 8 waves = 256 oc x 128 px (2 output rows).
// R6 changes vs R5 (all reg-neutral; R5 sat at 124/128 regs = hard cap):
//  - kc loop FULLY UNROLLED, no explicit A-rotation: scheduler hoists loads
//    ~2 steps deep under the 128-reg cap (R5's unroll-1 re-waited lgkm(0)
//    per step -> MfmaUtil 29%).
//  - A-loads via uniform SGPR base (wb += 8192 scalar) + per-lane voffset.
//  - split prologue: rows 0-2 -> barrier -> r=0,1 (48 steps, rows 0-2 only)
//    -> row 3 expansion (rr==3 threads, scoped regs) -> barrier -> r=2.
//  - setprio(1) around MFMA quad; bijective XCD block swizzle (896%8==0).
// C/D: col=l&31 (px), row=(q&3)+8*(q>>2)+4*(l>>5) (oc)  [HW-verified].
// ---------------------------------------------------------------------------
__global__ __launch_bounds__(512, 4) void conv_mfma(const u64* __restrict__ bp,
                                                    const char* __restrict__ wm,
                                                    float* __restrict__ y) {
    __shared__ __align__(16) u8 xl[61440];   // 4*14848 staged + w'<=65 slack
    int t = threadIdx.x;
    // XCD-aware bijective remap: each XCD gets 112 consecutive tiles = 4
    // consecutive n -> per-XCD-L2 bp slice 400KB (was: all 32 n on every XCD).
    int lin = blockIdx.x + 28 * blockIdx.y;
    int swb = (lin & 7) * 112 + (lin >> 3);
    int n   = swb / 28;
    int h0  = (swb - n * 28) * 2;

    int oct = t & 31, wseg = (t >> 5) & 3, rr = t >> 7;
    if (rr < 3)
        expand_row(bp, xl + rr * 14848, n, h0 + rr - 1, oct, wseg);
    __syncthreads();

    int wave = t >> 6, lane = t & 63;
    int ocg  = wave & 3;
    int pxg  = wave >> 2;
    int col  = lane & 31;
    int half = lane >> 5;
    int ocw  = ocg * 64;

    i32x16 acc[2][2] = {};
    const char* wb = wm;                       // uniform: stays in SGPR
    int aoff = (ocw + col) * 32 + half * 16;   // per-lane A voffset
    int h16  = half * 16;
    int swA = ((col + 0) & 15) << 4, cbA = (col + 0) * 256;
    int swB = ((col + 1) & 15) << 4, cbB = (col + 1) * 256;
    int swC = ((col + 2) & 15) << 4, cbC = (col + 2) * 256;

#define RS_BODY(ROWB, CBV, SWV)                                               \
    {   int cbase = (ROWB) + (CBV);                                           \
        _Pragma("unroll")                                                     \
        for (int k = 0; k < 8; ++k) {                                         \
            i32x4 a0 = *(const i32x4*)(wb + aoff);                            \
            i32x4 a1 = *(const i32x4*)(wb + aoff + 1024);                     \
            wb += 8192;                                                       \
            int ban = cbase + (((k * 32) + h16) ^ (SWV));                     \
            i32x4 b0 = *(const i32x4*)&xl[ban];                               \
            i32x4 b1 = *(const i32x4*)&xl[ban + 8192];                        \
            __builtin_amdgcn_s_setprio(1);                                    \
            acc[0][0] = __builtin_amdgcn_mfma_i32_32x32x32_i8(a0, b0, acc[0][0], 0, 0, 0); \
            acc[0][1] = __builtin_amdgcn_mfma_i32_32x32x32_i8(a0, b1, acc[0][1], 0, 0, 0); \
            acc[1][0] = __builtin_amdgcn_mfma_i32_32x32x32_i8(a1, b0, acc[1][0], 0, 0, 0); \
            acc[1][1] = __builtin_amdgcn_mfma_i32_32x32x32_i8(a1, b1, acc[1][1], 0, 0, 0); \
            __builtin_amdgcn_s_setprio(0);                                    \
        }                                                                     \
    }

    // Phase 1: r = 0,1 -> padded rows pxg+r in {0,1,2} only.
#pragma unroll 1
    for (int r = 0; r < 2; ++r) {
        int rowb = (pxg + r) * 14848;
#pragma unroll 1
        for (int s = 0; s < 3; ++s) {
            int swS = (s == 0) ? swA : (s == 1 ? swB : swC);
            int cbS = (s == 0) ? cbA : (s == 1 ? cbB : cbC);
            RS_BODY(rowb, cbS, swS)
        }
    }

    // Deferred row-3 expansion (read only in phase 2, after the barrier).
    if (rr == 3)
        expand_row(bp, xl + 3 * 14848, n, h0 + 2, oct, wseg);
    __syncthreads();

    // Phase 2: r = 2 -> rows pxg+2 in {2,3}.
    {
        int rowb = (pxg + 2) * 14848;
#pragma unroll 1
        for (int s = 0; s < 3; ++s) {
            int swS = (s == 0) ? swA : (s == 1 ? swB : swC);
            int cbS = (s == 0) ? cbA : (s == 1 ? cbB : cbC);
            RS_BODY(rowb, cbS, swS)
        }
    }
#undef RS_BODY

    int h = h0 + pxg;
    float* yb = y + (size_t)n * 256 * 3136 + (size_t)h * 56;
#pragma unroll
    for (int at = 0; at < 2; ++at) {
#pragma unroll
        for (int bt = 0; bt < 2; ++bt) {
            int w = bt * 32 + col;
            if (w < 56) {
#pragma unroll
                for (int q = 0; q < 16; ++q) {
                    int oc = ocw + at * 32 + (q & 3) + 8 * (q >> 2) + 4 * half;
                    yb[(size_t)oc * 3136 + w] = (float)acc[at][bt][q];
                }
            }
        }
    }
}

extern "C" void kernel_launch(void* const* d_in, const int* in_sizes, int n_in,
                              void* d_out, int out_size, void* d_ws, size_t ws_size,
                              hipStream_t stream) {
    const float* x  = (const float*)d_in[0];
    // d_in[1] (latent weight) unused in the STE forward value.
    const float* cb = (const float*)d_in[2];
    const int* enc  = (const int*)d_in[3];
    float* y        = (float*)d_out;

    char* wmc = (char*)d_ws + WM_OFF;
    u64*  bp  = (u64*)((char*)d_ws + BP_OFF);

    hipLaunchKernelGGL(prep, dim3(3872), dim3(256), 0, stream, enc, cb, wmc, x, bp);
    hipLaunchKernelGGL(conv_mfma, dim3(28, 32), dim3(512), 0, stream, bp, wmc, y);
}